// Round 10
// baseline (312.106 us; speedup 1.0000x reference)
//
#include <hip/hip_runtime.h>
#include <math.h>
#include <stdint.h>

#define CIN 256
#define HH 64
#define WW 64
#define HW 4096
#define CHW (CIN * HW) // 1048576

typedef __attribute__((ext_vector_type(8))) short short8;   // 8 bf16 = 4 VGPR (MFMA A/B frag)
typedef __attribute__((ext_vector_type(4))) float float4v;  // MFMA C/D frag
typedef __attribute__((ext_vector_type(2))) float f2a;

__device__ inline unsigned short f2bf(float f) {
    union { float f; uint32_t u; } v; v.f = f;
    return (unsigned short)((v.u + 0x7FFFu + ((v.u >> 16) & 1u)) >> 16);
}
__device__ inline float bf2f(unsigned short h) {
    union { uint32_t u; float f; } v; v.u = ((uint32_t)h) << 16;
    return v.f;
}
__device__ inline f2a ldg2(const float* p) {
    f2a r; __builtin_memcpy(&r, p, 8); return r;
}
// pack trunc_bf16(lo), trunc_bf16(hi) into one u32 via v_perm_b32 (1 instr)
__device__ inline uint32_t pack_bf_trunc(float lo, float hi) {
    union { float f; uint32_t u; } a, b; a.f = lo; b.f = hi;
    return __builtin_amdgcn_perm(b.u, a.u, 0x07060302u);
}

// ================= Kernel 1: offset conv partials, 8-way channel split — R9-proven ===============
__global__ __launch_bounds__(256) void k_offset_conv(
    const float* __restrict__ x, const float* __restrict__ w_off,
    float* __restrict__ off_part)
{
    __shared__ float red[4][64][18];
    const int bh = blockIdx.x, cg = blockIdx.y;
    const int b = bh >> 6, h = bh & 63;
    const int t = threadIdx.x;
    const int w = t & 63;
    const int wv = __builtin_amdgcn_readfirstlane(t >> 6);
    float acc[18];
#pragma unroll
    for (int i = 0; i < 18; ++i) acc[i] = 0.f;
    const float* xb = x + (size_t)b * CHW;
#pragma unroll
    for (int ci = 0; ci < 8; ++ci) {
        const int c = cg * 32 + wv * 8 + ci;
        const float* xc = xb + (size_t)c * HW;
        float r0 = (h > 0)  ? xc[(h - 1) * WW + w] : 0.f;
        float r1 =            xc[h * WW + w];
        float r2 = (h < 63) ? xc[(h + 1) * WW + w] : 0.f;
        float l0 = __shfl_up(r0, 1), l1 = __shfl_up(r1, 1), l2 = __shfl_up(r2, 1);
        float d0 = __shfl_down(r0, 1), d1 = __shfl_down(r1, 1), d2 = __shfl_down(r2, 1);
        if (w == 0)  { l0 = 0.f; l1 = 0.f; l2 = 0.f; }
        if (w == 63) { d0 = 0.f; d1 = 0.f; d2 = 0.f; }
        const float xv[9] = {l0, r0, d0, l1, r1, d1, l2, r2, d2};
        const float* wc = w_off + (size_t)c * 9;
#pragma unroll
        for (int co = 0; co < 18; ++co) {
            const float* wp = wc + (size_t)co * (CIN * 9);
#pragma unroll
            for (int k = 0; k < 9; ++k) acc[co] += wp[k] * xv[k];
        }
    }
#pragma unroll
    for (int co = 0; co < 18; ++co) red[wv][w][co] = acc[co];
    __syncthreads();
    if (t < 64) {
#pragma unroll
        for (int co = 0; co < 18; ++co) {
            float s = red[0][t][co] + red[1][t][co] + red[2][t][co] + red[3][t][co];
            off_part[((size_t)(cg * 128 + bh)) * 1152 + co * 64 + t] = s;
        }
    }
}

// ================= Kernel 2: patch-form bilinear params (sums 8 conv partials) — R9-proven =======
__global__ __launch_bounds__(256) void k_params(
    const float* __restrict__ off_part, const float* __restrict__ b_off,
    uint2* __restrict__ pbw, uint32_t* __restrict__ pba)
{
    const int bh = blockIdx.x;
    const int h = bh & 63;
    const int t = threadIdx.x;
    for (int r = 0; r < 3; ++r) {
        int sid = t + 256 * r;
        if (sid < 576) {
            int k = sid >> 6, ww = sid & 63;
            float dy = b_off[2 * k], dx = b_off[2 * k + 1];
#pragma unroll
            for (int g = 0; g < 8; ++g) {
                const float* pp = off_part + (size_t)(g * 128 + bh) * 1152;
                dy += pp[(2 * k) * 64 + ww];
                dx += pp[(2 * k + 1) * 64 + ww];
            }
            float py = (float)(h + k / 3 - 1) + dy;
            float px = (float)(ww + k % 3 - 1) + dx;
            float y0f = floorf(py), x0f = floorf(px);
            float fy = py - y0f, fx = px - x0f;
            int y0 = (int)y0f, x0 = (int)x0f;
            int yb = min(max(y0, 0), 62), xb = min(max(x0, 0), 62);
            float wr[2] = {0.f, 0.f}, wc[2] = {0.f, 0.f};
            if (y0 >= 0 && y0 < HH) wr[y0 - yb] += 1.f - fy;
            if (y0 + 1 >= 0 && y0 + 1 < HH) wr[y0 + 1 - yb] += fy;
            if (x0 >= 0 && x0 < WW) wc[x0 - xb] += 1.f - fx;
            if (x0 + 1 >= 0 && x0 + 1 < WW) wc[x0 + 1 - xb] += fx;
            uint2 pw;
            pw.x = (uint32_t)f2bf(wr[0] * wc[0]) | ((uint32_t)f2bf(wr[0] * wc[1]) << 16);
            pw.y = (uint32_t)f2bf(wr[1] * wc[0]) | ((uint32_t)f2bf(wr[1] * wc[1]) << 16);
            pbw[(size_t)bh * 576 + sid] = pw;
            pba[(size_t)bh * 576 + sid] = (uint32_t)(yb * WW + xb);
        }
    }
}

// ================= Kernel 3: W concat + bf16 cast — R3/R7-proven =================================
__global__ __launch_bounds__(256) void k_wcat(
    const float* __restrict__ wq, const float* __restrict__ wk, const float* __restrict__ wv_,
    const float* __restrict__ bq, const float* __restrict__ bk, const float* __restrict__ bv,
    unsigned short* __restrict__ wcat, float* __restrict__ bcat)
{
    int e = (blockIdx.x * 256 + threadIdx.x) * 4;
    const float* src;
    if (e < 32 * 2304)      src = wq + e;
    else if (e < 64 * 2304) src = wk + (e - 32 * 2304);
    else                    src = wv_ + (e - 64 * 2304);
    float4 v = *(const float4*)src;
    unsigned short o[4] = {f2bf(v.x), f2bf(v.y), f2bf(v.z), f2bf(v.w)};
    *(uint2*)(wcat + e) = *(const uint2*)o;
    if (blockIdx.x == 0 && threadIdx.x < 320) {
        int c = threadIdx.x;
        bcat[c] = c < 32 ? bq[c] : (c < 64 ? bk[c - 32] : bv[c - 64]);
    }
}

// ================= Kernel 4: sample S[n=8192][k=2304] bf16 — R3/R7-proven ========================
__global__ __launch_bounds__(256) void k_sample(
    const float* __restrict__ x, const uint2* __restrict__ pbw,
    const uint32_t* __restrict__ pba, unsigned short* __restrict__ sbuf)
{
    __shared__ uint2 prw[576];
    __shared__ uint32_t pra[576];
    __shared__ uint32_t T32[64 * 37];

    const int bh = blockIdx.x;
    const int cg = blockIdx.y;
    const int b = bh >> 6;
    const int t = threadIdx.x;
    const int p = t & 63;
    const int duo = t >> 6;

    for (int r = 0; r < 3; ++r) {
        int sid = t + 256 * r;
        if (sid < 576) { prw[sid] = pbw[(size_t)bh * 576 + sid]; pra[sid] = pba[(size_t)bh * 576 + sid]; }
    }
    __syncthreads();

    const float* xb = x + (size_t)b * CHW;
    const int fr = t >> 2, fc = t & 3;
    uint32_t* sb32 = (uint32_t*)sbuf;

    for (int c8 = 0; c8 < 8; ++c8) {
        const int ca = cg * 64 + c8 * 8 + duo * 2;
        const float* xpa = xb + (size_t)ca * HW;
        const float* xpb = xpa + HW;
        unsigned short vals[18];
#pragma unroll
        for (int tap = 0; tap < 9; ++tap) {
            uint2 wv2 = prw[tap * 64 + p];
            uint32_t base = pra[tap * 64 + p];
            float w00 = bf2f((unsigned short)(wv2.x & 0xFFFF));
            float w01 = bf2f((unsigned short)(wv2.x >> 16));
            float w10 = bf2f((unsigned short)(wv2.y & 0xFFFF));
            float w11 = bf2f((unsigned short)(wv2.y >> 16));
            f2a a0 = ldg2(xpa + base), a1 = ldg2(xpa + base + WW);
            f2a b0 = ldg2(xpb + base), b1 = ldg2(xpb + base + WW);
            vals[tap]     = f2bf(w00 * a0.x + w01 * a0.y + w10 * a1.x + w11 * a1.y);
            vals[9 + tap] = f2bf(w00 * b0.x + w01 * b0.y + w10 * b1.x + w11 * b1.y);
        }
        __syncthreads();
#pragma unroll
        for (int i = 0; i < 9; ++i)
            T32[p * 37 + duo * 9 + i] = (uint32_t)vals[2 * i] | ((uint32_t)vals[2 * i + 1] << 16);
        __syncthreads();
        {
            size_t gb = (size_t)(bh * 64 + fr) * 1152 + cg * 288 + c8 * 36 + fc * 9;
            const uint32_t* Tr = &T32[fr * 37 + fc * 9];
            uint32_t* gp = sb32 + gb;
#pragma unroll
            for (int i = 0; i < 9; ++i) gp[i] = Tr[i];
        }
    }
}

// ================= Kernel 5: GEMM C[320][8192] = Wcat . S^T — R3/R7-proven =======================
__global__ __launch_bounds__(256) void k_wgemm(
    const unsigned short* __restrict__ wcat, const float* __restrict__ bcat,
    const unsigned short* __restrict__ sbuf,
    unsigned short* __restrict__ qb16, unsigned short* __restrict__ kb16,
    unsigned short* __restrict__ vb16)
{
    __shared__ unsigned short Aw[64 * 36];
    __shared__ unsigned short Bl[64 * 36];

    const int nt = blockIdx.x;
    const int mt = blockIdx.y;
    const int t = threadIdx.x;
    const int lane = t & 63;
    const int l15 = lane & 15, quad = lane >> 4;
    const int wv = __builtin_amdgcn_readfirstlane(t >> 6);

    const int srow = t >> 2, sch = t & 3;
    const unsigned short* Ag = wcat + (size_t)(mt * 64 + srow) * 2304 + sch * 8;
    const unsigned short* Bg = sbuf + (size_t)(nt * 64 + srow) * 2304 + sch * 8;

    float4v acc[4];
#pragma unroll
    for (int s = 0; s < 4; ++s) acc[s] = (float4v){0.f, 0.f, 0.f, 0.f};

    for (int k0 = 0; k0 < 2304; k0 += 32) {
        uint4 av = *(const uint4*)(Ag + k0);
        uint4 bv = *(const uint4*)(Bg + k0);
        __syncthreads();
        *(uint4*)&Aw[srow * 36 + sch * 8] = av;
        *(uint4*)&Bl[srow * 36 + sch * 8] = bv;
        __syncthreads();
        short8 afr = *(const short8*)&Aw[(wv * 16 + l15) * 36 + quad * 8];
#pragma unroll
        for (int s = 0; s < 4; ++s) {
            short8 bfr = *(const short8*)&Bl[(s * 16 + l15) * 36 + quad * 8];
            acc[s] = __builtin_amdgcn_mfma_f32_16x16x32_bf16(afr, bfr, acc[s], 0, 0, 0);
        }
    }

    const int cobase = mt * 64 + wv * 16;
    unsigned short* ob; int lco; size_t nper;
    if (cobase < 32)      { ob = qb16; lco = cobase;      nper = (size_t)32 * HW; }
    else if (cobase < 64) { ob = kb16; lco = cobase - 32; nper = (size_t)32 * HW; }
    else                  { ob = vb16; lco = cobase - 64; nper = (size_t)256 * HW; }
    const int b = nt >> 6;
    unsigned short* obb = ob + (size_t)b * nper;
    float bias_r[4];
#pragma unroll
    for (int r = 0; r < 4; ++r) bias_r[r] = bcat[cobase + (quad << 2) + r];
    const int pb = (nt & 63) * 64;
#pragma unroll
    for (int s = 0; s < 4; ++s) {
#pragma unroll
        for (int r = 0; r < 4; ++r) {
            obb[(size_t)(lco + (quad << 2) + r) * HW + pb + s * 16 + l15]
                = f2bf(acc[s][r] + bias_r[r]);
        }
    }
}

// ================= Kernel 6: V re-layout into frag-order VF[jt][cc][jl] ==========================
// VF[jt][cc][jl] = V_attn[jt*32+jl][cc] (= vb16 flat [j*256+cc]). A PV B-frag then reads 1024
// contiguous bytes per wave (fully coalesced) — no LDS staging needed in k_attn.
__global__ __launch_bounds__(256) void k_vtrans(
    const unsigned short* __restrict__ vb16, unsigned short* __restrict__ vf)
{
    const int jt2 = blockIdx.x, b = blockIdx.y;   // jt2 covers global j-tiles 2*jt2, 2*jt2+1
    const int cc = threadIdx.x;
    const unsigned short* src = vb16 + (size_t)b * CHW + (size_t)(jt2 * 64) * 256 + cc;
    unsigned short* dst = vf + (size_t)b * CHW;
#pragma unroll
    for (int o = 0; o < 8; ++o) {
        union { uint4 v; unsigned short u[8]; } tmp;
#pragma unroll
        for (int j = 0; j < 8; ++j) tmp.u[j] = src[(o * 8 + j) * 256];   // coalesced over cc
        const int tg = 2 * jt2 + (o >> 2);
        *(uint4*)(dst + ((size_t)tg * 256 + cc) * 32 + (o & 3) * 8) = tmp.v;
    }
}

// ================= Kernel 7: flash attention, direct-global K/V frags, LDS only for P ============
// grid (128 qt of 32 q, 4 ch of 64 cc, B) = 1024 blocks; 256 thr = 4 waves:
// g = wv&1 (16 q), jh = wv>>1 (j-half). K frag read = 1024 contiguous B/wave (flat layout);
// V frag read = 1024 contiguous B/wave (VF layout). LDS ops/round: 2 uint2 stores + 1 b128 read.
#define SM_SHIFT 16.0f
__global__ __launch_bounds__(256) void k_attn(
    const unsigned short* __restrict__ qb16, const unsigned short* __restrict__ kb16,
    const unsigned short* __restrict__ vf, const float* __restrict__ x,
    const float* __restrict__ gamma, float* __restrict__ out)
{
    __shared__ unsigned short ptl[4][16 * 40];   // per-wave P buffer (A-layout), 5120 B
    __shared__ float red[2][64][20];             // jh=1 partials: 4x float4 + l, 10240 B

    const int qt = blockIdx.x, ch = blockIdx.y, b = blockIdx.z;
    const int t = threadIdx.x;
    const int wv = t >> 6;
    const int g = wv & 1, jh = wv >> 1;
    const int lane = t & 63;
    const int l15 = lane & 15, quad = lane >> 4;
    const int cc0 = ch * 64;

    const unsigned short* Qb = qb16 + (size_t)b * (32 * 4096);
    const unsigned short* Kb = kb16 + (size_t)b * (32 * 4096);
    const unsigned short* VB = vf + (size_t)b * CHW;

    const int q0 = qt * 32 + g * 16;
    short8 qfr = *(const short8*)(Qb + (size_t)(q0 + l15) * 32 + quad * 8);  // Q_attn[q][d] flat

    float l_i = 0.f;
    float4v acc[4];
#pragma unroll
    for (int s = 0; s < 4; ++s) acc[s] = (float4v){0.f, 0.f, 0.f, 0.f};
    unsigned short* pw = ptl[wv];

    for (int rnd = 0; rnd < 64; ++rnd) {
        const int jt = jh * 64 + rnd;       // global 32-j tile
        const int j0 = jt * 32;
        // ---- S^T = K Q^T, K frags direct-global (rows contiguous => coalesced) ----
        short8 kfr0 = *(const short8*)(Kb + (size_t)(j0 + l15) * 32 + quad * 8);
        short8 kfr1 = *(const short8*)(Kb + (size_t)(j0 + 16 + l15) * 32 + quad * 8);
        float4v s0 = (float4v){0.f, 0.f, 0.f, 0.f}, s1 = s0;
        s0 = __builtin_amdgcn_mfma_f32_16x16x32_bf16(kfr0, qfr, s0, 0, 0, 0);
        s1 = __builtin_amdgcn_mfma_f32_16x16x32_bf16(kfr1, qfr, s1, 0, 0, 0);
        // ---- max-free softmax numerator ----
        float p[8]; float ls = 0.f;
#pragma unroll
        for (int r = 0; r < 4; ++r) { p[r] = __expf(s0[r] - SM_SHIFT); ls += p[r]; }
#pragma unroll
        for (int r = 0; r < 4; ++r) { p[4 + r] = __expf(s1[r] - SM_SHIFT); ls += p[4 + r]; }
        l_i += ls;
        // ---- pack P (bf16 truncation via v_perm, 1 instr per pair) ----
        uint2 pk0, pk1;
        pk0.x = pack_bf_trunc(p[0], p[1]);  pk0.y = pack_bf_trunc(p[2], p[3]);
        pk1.x = pack_bf_trunc(p[4], p[5]);  pk1.y = pack_bf_trunc(p[6], p[7]);
        *(uint2*)&pw[l15 * 40 + (quad << 2)] = pk0;        // P[q=l15][j_local=quad*4+r]
        *(uint2*)&pw[l15 * 40 + 16 + (quad << 2)] = pk1;   // P[q=l15][16+quad*4+r]
        short8 pfr = *(const short8*)&pw[l15 * 40 + quad * 8];  // A[m=q][k=j] (wave-private)
        // ---- PV, V frags direct-global from VF (frag-order => coalesced) ----
        const unsigned short* vbase = VB + ((size_t)jt * 256 + cc0) * 32 + quad * 8;
#pragma unroll
        for (int s = 0; s < 4; ++s) {
            short8 vfr = *(const short8*)(vbase + (s * 16 + l15) * 32);
            acc[s] = __builtin_amdgcn_mfma_f32_16x16x32_bf16(pfr, vfr, acc[s], 0, 0, 0);
        }
    }

    l_i += __shfl_xor(l_i, 16);
    l_i += __shfl_xor(l_i, 32);

    __syncthreads();
    if (jh == 1) {
#pragma unroll
        for (int s = 0; s < 4; ++s) *(float4v*)&red[g][lane][s * 4] = acc[s];
        red[g][lane][16] = l_i;
    }
    __syncthreads();
    if (jh == 0) {
#pragma unroll
        for (int s = 0; s < 4; ++s) {
            float4v o = *(const float4v*)&red[g][lane][s * 4];
            acc[s][0] += o[0]; acc[s][1] += o[1]; acc[s][2] += o[2]; acc[s][3] += o[3];
        }
        l_i += red[g][lane][16];
        float lr[4];
#pragma unroll
        for (int r = 0; r < 4; ++r) lr[r] = __shfl(l_i, (quad << 2) + r);
        const float gm = gamma[0];
        const float* xb = x + (size_t)b * CHW;
        float* ob = out + (size_t)b * CHW;
#pragma unroll
        for (int s = 0; s < 4; ++s) {
#pragma unroll
            for (int r = 0; r < 4; ++r) {
                int q = q0 + (quad << 2) + r;
                int cc = cc0 + s * 16 + l15;
                size_t idx = (size_t)q * 256 + cc;
                ob[idx] = gm * (acc[s][r] / lr[r]) + xb[idx];
            }
        }
    }
}

extern "C" void kernel_launch(void* const* d_in, const int* in_sizes, int n_in,
                              void* d_out, int out_size, void* d_ws, size_t ws_size,
                              hipStream_t stream)
{
    (void)in_sizes; (void)n_in; (void)out_size; (void)ws_size;
    const float* x     = (const float*)d_in[0];
    const float* w_off = (const float*)d_in[1];
    const float* b_off = (const float*)d_in[2];
    const float* wq    = (const float*)d_in[3];
    const float* bq    = (const float*)d_in[4];
    const float* wk    = (const float*)d_in[5];
    const float* bk    = (const float*)d_in[6];
    const float* wv    = (const float*)d_in[7];
    const float* bv    = (const float*)d_in[8];
    const float* gamma = (const float*)d_in[9];
    float* out = (float*)d_out;

    // ws layout (bytes): R7/R8/R9-proven footprint; vb16T region now holds VF (frag-order V).
    char* ws = (char*)d_ws;
    uint2*          pbw     = (uint2*)(ws + 589824);             //  589824
    uint32_t*       pba     = (uint32_t*)(ws + 1179648);         //  294912
    unsigned short* qb16    = (unsigned short*)(ws + 1474560);   //  524288 [32 c][4096 p] flat
    unsigned short* kb16    = (unsigned short*)(ws + 1998848);   //  524288 [32 c][4096 p] flat
    unsigned short* vfb     = (unsigned short*)(ws + 2523136);   // 4194304 VF[jt][cc][jl]
    unsigned short* wcat    = (unsigned short*)(ws + 6717440);   // 1474560
    float*          bcat    = (float*)(ws + 8192000);            //    2048
    unsigned short* sbuf    = (unsigned short*)(ws + 8194048);   // 37748736
    // d_out scratch (8 MB), time-sliced: off_part (4.72 MB) until k_params; then vb16 (4 MB)
    // until k_vtrans; k_attn overwrites all of d_out last.
    float*          off_part = (float*)d_out;
    unsigned short* vb16     = (unsigned short*)d_out;

    k_offset_conv<<<dim3(128, 8), 256, 0, stream>>>(x, w_off, off_part);
    k_params<<<dim3(128), 256, 0, stream>>>(off_part, b_off, pbw, pba);
    k_wcat<<<dim3(720), 256, 0, stream>>>(wq, wk, wv, bq, bk, bv, wcat, bcat);
    k_sample<<<dim3(2 * HH, 4), 256, 0, stream>>>(x, pbw, pba, sbuf);
    k_wgemm<<<dim3(2 * HH, 5), 256, 0, stream>>>(wcat, bcat, sbuf, qb16, kb16, vb16);
    k_vtrans<<<dim3(64, 2), 256, 0, stream>>>(vb16, vfb);
    k_attn<<<dim3(128, 4, 2), 256, 0, stream>>>(qb16, kb16, vfb, x, gamma, out);
}

// Round 11
// 286.397 us; speedup vs baseline: 1.0898x; 1.0898x over previous
//
#include <hip/hip_runtime.h>
#include <math.h>
#include <stdint.h>

#define CIN 256
#define HH 64
#define WW 64
#define HW 4096
#define CHW (CIN * HW) // 1048576

typedef __attribute__((ext_vector_type(8))) short short8;   // 8 bf16 = 4 VGPR (MFMA A/B frag)
typedef __attribute__((ext_vector_type(4))) float float4v;  // MFMA C/D frag
typedef __attribute__((ext_vector_type(2))) float f2a;

__device__ inline unsigned short f2bf(float f) {
    union { float f; uint32_t u; } v; v.f = f;
    return (unsigned short)((v.u + 0x7FFFu + ((v.u >> 16) & 1u)) >> 16);
}
__device__ inline float bf2f(unsigned short h) {
    union { uint32_t u; float f; } v; v.u = ((uint32_t)h) << 16;
    return v.f;
}
__device__ inline f2a ldg2(const float* p) {
    f2a r; __builtin_memcpy(&r, p, 8); return r;
}

// ================= Kernel 1: offset conv partials, 8-way channel split — R9-proven ===============
__global__ __launch_bounds__(256) void k_offset_conv(
    const float* __restrict__ x, const float* __restrict__ w_off,
    float* __restrict__ off_part)
{
    __shared__ float red[4][64][18];
    const int bh = blockIdx.x, cg = blockIdx.y;
    const int b = bh >> 6, h = bh & 63;
    const int t = threadIdx.x;
    const int w = t & 63;
    const int wv = __builtin_amdgcn_readfirstlane(t >> 6);
    float acc[18];
#pragma unroll
    for (int i = 0; i < 18; ++i) acc[i] = 0.f;
    const float* xb = x + (size_t)b * CHW;
#pragma unroll
    for (int ci = 0; ci < 8; ++ci) {
        const int c = cg * 32 + wv * 8 + ci;
        const float* xc = xb + (size_t)c * HW;
        float r0 = (h > 0)  ? xc[(h - 1) * WW + w] : 0.f;
        float r1 =            xc[h * WW + w];
        float r2 = (h < 63) ? xc[(h + 1) * WW + w] : 0.f;
        float l0 = __shfl_up(r0, 1), l1 = __shfl_up(r1, 1), l2 = __shfl_up(r2, 1);
        float d0 = __shfl_down(r0, 1), d1 = __shfl_down(r1, 1), d2 = __shfl_down(r2, 1);
        if (w == 0)  { l0 = 0.f; l1 = 0.f; l2 = 0.f; }
        if (w == 63) { d0 = 0.f; d1 = 0.f; d2 = 0.f; }
        const float xv[9] = {l0, r0, d0, l1, r1, d1, l2, r2, d2};
        const float* wc = w_off + (size_t)c * 9;
#pragma unroll
        for (int co = 0; co < 18; ++co) {
            const float* wp = wc + (size_t)co * (CIN * 9);
#pragma unroll
            for (int k = 0; k < 9; ++k) acc[co] += wp[k] * xv[k];
        }
    }
#pragma unroll
    for (int co = 0; co < 18; ++co) red[wv][w][co] = acc[co];
    __syncthreads();
    if (t < 64) {
#pragma unroll
        for (int co = 0; co < 18; ++co) {
            float s = red[0][t][co] + red[1][t][co] + red[2][t][co] + red[3][t][co];
            off_part[((size_t)(cg * 128 + bh)) * 1152 + co * 64 + t] = s;
        }
    }
}

// ================= Kernel 2: patch-form bilinear params (sums 8 conv partials) — R9-proven =======
__global__ __launch_bounds__(256) void k_params(
    const float* __restrict__ off_part, const float* __restrict__ b_off,
    uint2* __restrict__ pbw, uint32_t* __restrict__ pba)
{
    const int bh = blockIdx.x;
    const int h = bh & 63;
    const int t = threadIdx.x;
    for (int r = 0; r < 3; ++r) {
        int sid = t + 256 * r;
        if (sid < 576) {
            int k = sid >> 6, ww = sid & 63;
            float dy = b_off[2 * k], dx = b_off[2 * k + 1];
#pragma unroll
            for (int g = 0; g < 8; ++g) {
                const float* pp = off_part + (size_t)(g * 128 + bh) * 1152;
                dy += pp[(2 * k) * 64 + ww];
                dx += pp[(2 * k + 1) * 64 + ww];
            }
            float py = (float)(h + k / 3 - 1) + dy;
            float px = (float)(ww + k % 3 - 1) + dx;
            float y0f = floorf(py), x0f = floorf(px);
            float fy = py - y0f, fx = px - x0f;
            int y0 = (int)y0f, x0 = (int)x0f;
            int yb = min(max(y0, 0), 62), xb = min(max(x0, 0), 62);
            float wr[2] = {0.f, 0.f}, wc[2] = {0.f, 0.f};
            if (y0 >= 0 && y0 < HH) wr[y0 - yb] += 1.f - fy;
            if (y0 + 1 >= 0 && y0 + 1 < HH) wr[y0 + 1 - yb] += fy;
            if (x0 >= 0 && x0 < WW) wc[x0 - xb] += 1.f - fx;
            if (x0 + 1 >= 0 && x0 + 1 < WW) wc[x0 + 1 - xb] += fx;
            uint2 pw;
            pw.x = (uint32_t)f2bf(wr[0] * wc[0]) | ((uint32_t)f2bf(wr[0] * wc[1]) << 16);
            pw.y = (uint32_t)f2bf(wr[1] * wc[0]) | ((uint32_t)f2bf(wr[1] * wc[1]) << 16);
            pbw[(size_t)bh * 576 + sid] = pw;
            pba[(size_t)bh * 576 + sid] = (uint32_t)(yb * WW + xb);
        }
    }
}

// ================= Kernel 3: W concat + bf16 cast into FRAG-NATIVE layout ========================
// WF[strip=co>>4][kt=k>>5][co&15][k&31]: an A-frag read (16 co x 32 k block) is then 1024
// contiguous bytes per wave — fully coalesced, no 64-line scatter.
__global__ __launch_bounds__(256) void k_wcat(
    const float* __restrict__ wq, const float* __restrict__ wk, const float* __restrict__ wv_,
    const float* __restrict__ bq, const float* __restrict__ bk, const float* __restrict__ bv,
    unsigned short* __restrict__ wf, float* __restrict__ bcat)
{
    int e = (blockIdx.x * 256 + threadIdx.x) * 4;   // flat co*2304+k, 4 consecutive k
    const float* src;
    if (e < 32 * 2304)      src = wq + e;
    else if (e < 64 * 2304) src = wk + (e - 32 * 2304);
    else                    src = wv_ + (e - 64 * 2304);
    float4 v = *(const float4*)src;
    unsigned short o[4] = {f2bf(v.x), f2bf(v.y), f2bf(v.z), f2bf(v.w)};
    int co = e / 2304;
    int k = e - co * 2304;
    size_t d = ((size_t)(co >> 4) * 72 + (k >> 5)) * 512 + (size_t)(co & 15) * 32 + (k & 31);
    *(uint2*)(wf + d) = *(const uint2*)o;
    if (blockIdx.x == 0 && threadIdx.x < 320) {
        int c = threadIdx.x;
        bcat[c] = c < 32 ? bq[c] : (c < 64 ? bk[c - 32] : bv[c - 64]);
    }
}

// ================= Kernel 4: FUSED sample + GEMM (replaces k_sample + k_wgemm) ===================
// grid 512: b = blk>>8, 16-px tile. 256 thr = 4 waves. Wave wvid owns co strips st*64+wvid*16
// (st=0..4, covers all 320 co; 16-strips never cross q/k/v boundaries). Per 32-k step: each
// thread samples 2 values into the 16x32 B-tile (LDS), A-frags stream coalesced from WF,
// 5 MFMA accumulate. Outputs in R3-proven [co][p] layouts (raw-reshape semantics).
__global__ __launch_bounds__(256) void k_dgemm(
    const float* __restrict__ x, const uint2* __restrict__ pbw, const uint32_t* __restrict__ pba,
    const unsigned short* __restrict__ wf, const float* __restrict__ bcat,
    unsigned short* __restrict__ qb16, unsigned short* __restrict__ kb16,
    unsigned short* __restrict__ vb16)
{
    __shared__ uint2 prw2[144];      // [nl*9 + tap]
    __shared__ uint32_t pra2[144];
    __shared__ uint32_t T32[16 * 20]; // 16 px rows x 20 words (32 k bf16 + pad)

    const int blk = blockIdx.x;
    const int b = blk >> 8;
    const int p0 = (blk & 255) * 16;
    const int bh = b * 64 + (p0 >> 6);
    const int w0 = p0 & 63;

    const int t = threadIdx.x;
    const int lane = t & 63;
    const int l15 = lane & 15, quad = lane >> 4;
    const int wvid = __builtin_amdgcn_readfirstlane(t >> 6);

    if (t < 144) {
        int nl9 = t / 9, tap = t - nl9 * 9;
        int src = bh * 576 + tap * 64 + w0 + nl9;
        prw2[nl9 * 9 + tap] = pbw[src];
        pra2[nl9 * 9 + tap] = pba[src];
    }

    const float* xb = x + (size_t)b * CHW;
    const int nl = t & 15;      // pixel-local
    const int kh = t >> 4;      // 0..15 -> k pair 2kh, 2kh+1

    float4v acc[5];
#pragma unroll
    for (int s = 0; s < 5; ++s) acc[s] = (float4v){0.f, 0.f, 0.f, 0.f};

    const unsigned short* ap[5];
#pragma unroll
    for (int s = 0; s < 5; ++s)
        ap[s] = wf + (size_t)(s * 4 + wvid) * 72 * 512 + (size_t)l15 * 32 + quad * 8;

    __syncthreads();   // prm ready

    for (int kt = 0; kt < 72; ++kt) {
        // --- A-frag loads (coalesced 1024B/wave, independent of sampling) ---
        uint4 a[5];
#pragma unroll
        for (int s = 0; s < 5; ++s) a[s] = *(const uint4*)(ap[s] + kt * 512);

        // --- sample 2 values ---
        float v2[2];
#pragma unroll
        for (int i = 0; i < 2; ++i) {
            int kd = kt * 32 + kh * 2 + i;
            int c = (kd * 7282) >> 16;      // exact /9 for kd < 2304
            int tap = kd - c * 9;
            uint2 wv2 = prw2[nl * 9 + tap];
            uint32_t base = pra2[nl * 9 + tap];
            const float* xp = xb + (size_t)c * HW + base;
            f2a r0 = ldg2(xp), r1 = ldg2(xp + WW);
            v2[i] = bf2f((unsigned short)(wv2.x & 0xFFFF)) * r0.x
                  + bf2f((unsigned short)(wv2.x >> 16)) * r0.y
                  + bf2f((unsigned short)(wv2.y & 0xFFFF)) * r1.x
                  + bf2f((unsigned short)(wv2.y >> 16)) * r1.y;
        }
        uint32_t packed = (uint32_t)f2bf(v2[0]) | ((uint32_t)f2bf(v2[1]) << 16);
        __syncthreads();   // WAR: prev frag reads done
        T32[nl * 20 + kh] = packed;
        __syncthreads();   // RAW: tile visible
        short8 bfr = *(const short8*)((const unsigned short*)T32 + l15 * 40 + quad * 8);
#pragma unroll
        for (int s = 0; s < 5; ++s)
            acc[s] = __builtin_amdgcn_mfma_f32_16x16x32_bf16(*(const short8*)&a[s], bfr, acc[s], 0, 0, 0);
    }

    // --- epilogue: D[row=co-local quad*4+r][col=px l15], bias, [co][p] stores (R3 semantics) ---
#pragma unroll
    for (int s = 0; s < 5; ++s) {
        const int cobase = s * 64 + wvid * 16;
        unsigned short* ob; int lco; size_t nper;
        if (cobase < 32)      { ob = qb16; lco = cobase;      nper = (size_t)32 * HW; }
        else if (cobase < 64) { ob = kb16; lco = cobase - 32; nper = (size_t)32 * HW; }
        else                  { ob = vb16; lco = cobase - 64; nper = (size_t)256 * HW; }
        unsigned short* obb = ob + (size_t)b * nper;
#pragma unroll
        for (int r = 0; r < 4; ++r) {
            float val = acc[s][r] + bcat[cobase + (quad << 2) + r];
            obb[(size_t)(lco + (quad << 2) + r) * HW + p0 + l15] = f2bf(val);
        }
    }
}

// ================= Kernel 5: V re-layout [j][cc] -> [cc][j] — R9-proven ==========================
__global__ __launch_bounds__(256) void k_vtrans(
    const unsigned short* __restrict__ vb16, unsigned short* __restrict__ vb16T)
{
    const int jt = blockIdx.x, b = blockIdx.y;
    const int cc = threadIdx.x;
    const unsigned short* src = vb16 + (size_t)b * CHW + (size_t)(jt * 64) * 256 + cc;
    unsigned short* dst = vb16T + (size_t)b * CHW + (size_t)cc * 4096 + jt * 64;
#pragma unroll
    for (int o = 0; o < 8; ++o) {
        union { uint4 v; unsigned short u[8]; } tmp;
#pragma unroll
        for (int j = 0; j < 8; ++j) tmp.u[j] = src[(o * 8 + j) * 256];
        *(uint4*)(dst + o * 8) = tmp.v;
    }
}

// ================= Kernel 6: flash attention with LDS-staged K/V tiles — R9-proven (80.5 us) =====
#define SM_SHIFT 16.0f
__global__ __launch_bounds__(256) void k_attn(
    const unsigned short* __restrict__ qb16, const unsigned short* __restrict__ kb16,
    const unsigned short* __restrict__ vt, const float* __restrict__ x,
    const float* __restrict__ gamma, float* __restrict__ out)
{
    __shared__ unsigned short ptl[4][16 * 40];
    __shared__ unsigned short Vt[2][64][40];
    __shared__ unsigned short Kt[2][32][36];
    __shared__ float red[2][64][20];

    const int qt = blockIdx.x, ch = blockIdx.y, b = blockIdx.z;
    const int t = threadIdx.x;
    const int lane = t & 63;
    const int wv = t >> 6;
    const int g = wv & 1, jh = wv >> 1;
    const int l15 = lane & 15, quad = lane >> 4;
    const int cc0 = ch * 64;

    const unsigned short* Qb = qb16 + (size_t)b * (32 * 4096);
    const unsigned short* Kb = kb16 + (size_t)b * (32 * 4096);
    const unsigned short* VT = vt + (size_t)b * CHW;

    const int q0 = qt * 32 + g * 16;
    short8 qfr = *(const short8*)(Qb + (size_t)(q0 + l15) * 32 + quad * 8);

    const int vcc = t >> 2, voff = (t & 3) * 8;
    const int ktile = t >> 7, ktl = t & 127;
    const int krow = ktl >> 2, koff = (ktl & 3) * 8;

    float l_i = 0.f;
    float4v acc[4];
#pragma unroll
    for (int s = 0; s < 4; ++s) acc[s] = (float4v){0.f, 0.f, 0.f, 0.f};
    unsigned short* pw = ptl[wv];

    for (int rnd = 0; rnd < 64; ++rnd) {
        const int j0a = rnd * 32;
        uint4 v0 = *(const uint4*)(VT + (size_t)(cc0 + vcc) * 4096 + j0a + voff);
        uint4 v1 = *(const uint4*)(VT + (size_t)(cc0 + vcc) * 4096 + 2048 + j0a + voff);
        uint4 kv = *(const uint4*)(Kb + (size_t)(ktile * 2048 + j0a + krow) * 32 + koff);
        __syncthreads();
        *(uint4*)&Vt[0][vcc][voff] = v0;
        *(uint4*)&Vt[1][vcc][voff] = v1;
        *(uint4*)&Kt[ktile][krow][koff] = kv;
        __syncthreads();
        short8 kfr0 = *(const short8*)&Kt[jh][l15][quad * 8];
        short8 kfr1 = *(const short8*)&Kt[jh][16 + l15][quad * 8];
        float4v s0 = (float4v){0.f, 0.f, 0.f, 0.f}, s1 = s0;
        s0 = __builtin_amdgcn_mfma_f32_16x16x32_bf16(kfr0, qfr, s0, 0, 0, 0);
        s1 = __builtin_amdgcn_mfma_f32_16x16x32_bf16(kfr1, qfr, s1, 0, 0, 0);
        float p[8]; float ls = 0.f;
#pragma unroll
        for (int r = 0; r < 4; ++r) { p[r] = __expf(s0[r] - SM_SHIFT); ls += p[r]; }
#pragma unroll
        for (int r = 0; r < 4; ++r) { p[4 + r] = __expf(s1[r] - SM_SHIFT); ls += p[4 + r]; }
        l_i += ls;
        union { uint2 v; unsigned short u[4]; } pk0, pk1;
#pragma unroll
        for (int r = 0; r < 4; ++r) { pk0.u[r] = f2bf(p[r]); pk1.u[r] = f2bf(p[4 + r]); }
        *(uint2*)&pw[l15 * 40 + (quad << 2)] = pk0.v;
        *(uint2*)&pw[l15 * 40 + 16 + (quad << 2)] = pk1.v;
        short8 pfr = *(const short8*)&pw[l15 * 40 + quad * 8];
#pragma unroll
        for (int s = 0; s < 4; ++s) {
            short8 vfr = *(const short8*)&Vt[jh][s * 16 + l15][quad * 8];
            acc[s] = __builtin_amdgcn_mfma_f32_16x16x32_bf16(pfr, vfr, acc[s], 0, 0, 0);
        }
    }

    l_i += __shfl_xor(l_i, 16);
    l_i += __shfl_xor(l_i, 32);

    __syncthreads();
    if (jh == 1) {
#pragma unroll
        for (int s = 0; s < 4; ++s) *(float4v*)&red[g][lane][s * 4] = acc[s];
        red[g][lane][16] = l_i;
    }
    __syncthreads();
    if (jh == 0) {
#pragma unroll
        for (int s = 0; s < 4; ++s) {
            float4v o = *(const float4v*)&red[g][lane][s * 4];
            acc[s][0] += o[0]; acc[s][1] += o[1]; acc[s][2] += o[2]; acc[s][3] += o[3];
        }
        l_i += red[g][lane][16];
        float lr[4];
#pragma unroll
        for (int r = 0; r < 4; ++r) lr[r] = __shfl(l_i, (quad << 2) + r);
        const float gm = gamma[0];
        const float* xb = x + (size_t)b * CHW;
        float* ob = out + (size_t)b * CHW;
#pragma unroll
        for (int s = 0; s < 4; ++s) {
#pragma unroll
            for (int r = 0; r < 4; ++r) {
                int q = q0 + (quad << 2) + r;
                int cc = cc0 + s * 16 + l15;
                size_t idx = (size_t)q * 256 + cc;
                ob[idx] = gm * (acc[s][r] / lr[r]) + xb[idx];
            }
        }
    }
}

extern "C" void kernel_launch(void* const* d_in, const int* in_sizes, int n_in,
                              void* d_out, int out_size, void* d_ws, size_t ws_size,
                              hipStream_t stream)
{
    (void)in_sizes; (void)n_in; (void)out_size; (void)ws_size;
    const float* x     = (const float*)d_in[0];
    const float* w_off = (const float*)d_in[1];
    const float* b_off = (const float*)d_in[2];
    const float* wq    = (const float*)d_in[3];
    const float* bq    = (const float*)d_in[4];
    const float* wk    = (const float*)d_in[5];
    const float* bk    = (const float*)d_in[6];
    const float* wv    = (const float*)d_in[7];
    const float* bv    = (const float*)d_in[8];
    const float* gamma = (const float*)d_in[9];
    float* out = (float*)d_out;

    // ws layout (bytes): same proven offsets; sbuf no longer used (fused kernel).
    char* ws = (char*)d_ws;
    uint2*          pbw     = (uint2*)(ws + 589824);             //  589824
    uint32_t*       pba     = (uint32_t*)(ws + 1179648);         //  294912
    unsigned short* qb16    = (unsigned short*)(ws + 1474560);   //  524288 [32 c][4096 p] flat
    unsigned short* kb16    = (unsigned short*)(ws + 1998848);   //  524288 [32 c][4096 p] flat
    unsigned short* vb16T   = (unsigned short*)(ws + 2523136);   // 4194304 [cc][4096 j]
    unsigned short* wfb     = (unsigned short*)(ws + 6717440);   // 1474560 frag-order W
    float*          bcat    = (float*)(ws + 8192000);            //    2048
    // d_out scratch (8 MB), time-sliced: off_part (4.72 MB) until k_params; then vb16 (4 MB)
    // until k_vtrans; k_attn overwrites all of d_out last.
    float*          off_part = (float*)d_out;
    unsigned short* vb16     = (unsigned short*)d_out;

    k_offset_conv<<<dim3(128, 8), 256, 0, stream>>>(x, w_off, off_part);
    k_params<<<dim3(128), 256, 0, stream>>>(off_part, b_off, pbw, pba);
    k_wcat<<<dim3(720), 256, 0, stream>>>(wq, wk, wv, bq, bk, bv, wfb, bcat);
    k_dgemm<<<dim3(512), 256, 0, stream>>>(x, pbw, pba, wfb, bcat, qb16, kb16, vb16);
    k_vtrans<<<dim3(64, 2), 256, 0, stream>>>(vb16, vb16T);
    k_attn<<<dim3(128, 4, 2), 256, 0, stream>>>(qb16, kb16, vb16T, x, gamma, out);
}